// Round 2
// baseline (211.498 us; speedup 1.0000x reference)
//
#include <hip/hip_runtime.h>
#include <hip/hip_bf16.h>

#define IN_DIM    1024
#define HEAD_DIM  64
#define NUM_HEADS 16
#define SEQ       4096

// 1/sqrt(64) * log2(e), folded into Q (fp32, pre-bf16-cast). Softmax computed
// with exp2 (v_exp_f32 IS 2^x) -> no per-element ln2 prescale mul in attn.
#define QSCALE 0.18033688011112042f

typedef __bf16 bf16;
typedef __attribute__((ext_vector_type(4))) __bf16 bf16x4;
typedef __attribute__((ext_vector_type(8))) __bf16 bf16x8;
typedef __attribute__((ext_vector_type(4))) float floatx4;
typedef __attribute__((ext_vector_type(16))) float floatx16;
typedef __attribute__((ext_vector_type(4))) unsigned uint32x4;

__device__ __forceinline__ void async16(bf16* lds, const bf16* g) {
    __builtin_amdgcn_global_load_lds(
        (const __attribute__((address_space(1))) unsigned int*)g,
        (__attribute__((address_space(3))) unsigned int*)lds, 16, 0, 0);
}

__device__ __forceinline__ unsigned cvtpk_bf16(float lo, float hi) {
    unsigned r;
    asm("v_cvt_pk_bf16_f32 %0, %1, %2" : "=v"(r) : "v"(lo), "v"(hi));
    return r;
}

// v_permlane32_swap_b32 vdst, vsrc (CDNA4): vdst[32:63] <-> vsrc[0:31]
// ("odd row of first operand swaps with even row of second").
__device__ __forceinline__ void permswap(unsigned& a, unsigned& b) {
    asm("v_permlane32_swap_b32 %0, %1" : "+v"(a), "+v"(b));
}

// ---------------------------------------------------------------------------
// ws layout: hb @0 (8MB) | Wt @8MB (6MB, n-major) | Qb @14MB | Kb @22MB | Vt @30MB
// ---------------------------------------------------------------------------

__global__ void mha_conv_h(const float* __restrict__ h, bf16* __restrict__ hb) {
    int i = blockIdx.x * blockDim.x + threadIdx.x;
    float4 v = ((const float4*)h)[i];
    bf16x4 r;
    r[0] = (bf16)v.x; r[1] = (bf16)v.y; r[2] = (bf16)v.z; r[3] = (bf16)v.w;
    ((bf16x4*)hb)[i] = r;
}

__global__ void mha_conv_wt(const float* __restrict__ Wq, const float* __restrict__ Wk,
                            const float* __restrict__ Wv, bf16* __restrict__ Wt) {
    __shared__ bf16 tile[64][65];
    const int mat = blockIdx.z;
    const float* W = (mat == 0) ? Wq : (mat == 1) ? Wk : Wv;
    const int k0 = blockIdx.y * 64, n0 = blockIdx.x * 64;
    const int tn = threadIdx.x & 63, tq = threadIdx.x >> 6;
#pragma unroll
    for (int i = 0; i < 16; ++i) {
        int kk = tq + i * 4;
        tile[kk][tn] = (bf16)W[(size_t)(k0 + kk) * 1024 + n0 + tn];
    }
    __syncthreads();
#pragma unroll
    for (int i = 0; i < 16; ++i) {
        int nn = tq + i * 4;
        Wt[((size_t)mat << 20) + (size_t)(n0 + nn) * 1024 + k0 + tn] = tile[tn][nn];
    }
}

// ---------------------------------------------------------------------------
// QKV GEMM, m97-style: 128x128 tile, BK=32, global_load_lds staging,
// XOR-swizzled chunks so frag ds_read_b128 lands 2-way (free).  UNCHANGED.
// ---------------------------------------------------------------------------
__launch_bounds__(256)
__global__ void mha_qkv_gemm(const bf16* __restrict__ hb, const bf16* __restrict__ Wt,
                             const float* __restrict__ bq, const float* __restrict__ bk,
                             const float* __restrict__ bv,
                             bf16* __restrict__ Qb, bf16* __restrict__ Kb,
                             bf16* __restrict__ Vt) {
    __shared__ __align__(16) bf16 As[128 * 32];
    __shared__ __align__(16) bf16 Bs[128 * 32];

    const int lane = threadIdx.x & 63;
    const int wave = threadIdx.x >> 6;
    const int l16  = lane & 15;
    const int quad = lane >> 4;
    const int wm   = wave & 1;
    const int wn   = wave >> 1;

    const int m0  = blockIdx.x * 128;
    const int n0  = blockIdx.y * 128;
    const int mat = n0 >> 10;
    const int nc0 = n0 & 1023;

    const bf16* Wp = Wt + ((size_t)mat << 20);

    floatx4 acc[4][4] = {};
    const int swz = (l16 >> 1) & 3;

    for (int k0 = 0; k0 < IN_DIM; k0 += 32) {
#pragma unroll
        for (int r = 0; r < 2; ++r) {
            int g = wave * 128 + r * 64 + lane;
            int row = g >> 2, c = g & 3;
            int gc = c ^ ((row >> 1) & 3);
            bf16* ldsbase_a = As + (size_t)(wave * 128 + r * 64) * 8;
            bf16* ldsbase_b = Bs + (size_t)(wave * 128 + r * 64) * 8;
            async16(ldsbase_a, hb + (size_t)(m0 + row) * IN_DIM + k0 + gc * 8);
            async16(ldsbase_b, Wp + (size_t)(nc0 + row) * IN_DIM + k0 + gc * 8);
        }
        __syncthreads();

        bf16x8 af[4], bf[4];
#pragma unroll
        for (int mt = 0; mt < 4; ++mt)
            af[mt] = *(const bf16x8*)(As + (size_t)(wm * 64 + mt * 16 + l16) * 32
                                      + ((quad ^ swz) * 8));
#pragma unroll
        for (int nt = 0; nt < 4; ++nt)
            bf[nt] = *(const bf16x8*)(Bs + (size_t)(wn * 64 + nt * 16 + l16) * 32
                                      + ((quad ^ swz) * 8));
#pragma unroll
        for (int mt = 0; mt < 4; ++mt)
#pragma unroll
            for (int nt = 0; nt < 4; ++nt)
                acc[mt][nt] = __builtin_amdgcn_mfma_f32_16x16x32_bf16(af[mt], bf[nt],
                                                                      acc[mt][nt], 0, 0, 0);
        __syncthreads();
    }

    const float* bias = (mat == 0) ? bq : (mat == 1) ? bk : bv;
#pragma unroll
    for (int nt = 0; nt < 4; ++nt) {
        int nc = nc0 + wn * 64 + nt * 16 + l16;
        float bb = bias[nc];
        int head = nc >> 6, d = nc & 63;
#pragma unroll
        for (int mt = 0; mt < 4; ++mt)
#pragma unroll
            for (int r = 0; r < 4; ++r) {
                int srow = m0 + wm * 64 + mt * 16 + quad * 4 + r;
                float v = acc[mt][nt][r] + bb;
                if (mat == 0)
                    Qb[((size_t)head * SEQ + srow) * HEAD_DIM + d] = (bf16)(v * QSCALE);
                else if (mat == 1)
                    Kb[((size_t)head * SEQ + srow) * HEAD_DIM + d] = (bf16)v;
                else
                    Vt[((size_t)head * HEAD_DIM + d) * SEQ + srow] = (bf16)v;
            }
    }
}

// ---------------------------------------------------------------------------
// Attention v2b: 4 waves x 32 q-rows (128 q/block), 32x32x16 MFMA, in-register
// P transpose (cvt_pk_bf16 + permlane32_swap) -- no Ps LDS round-trip.
// R1 bug: permlane32_swap direction is vdst.hi <-> vsrc.lo; arg order fixed.
//
// Layouts (guide-verified):
//   mfma_f32_32x32x16: A row=l&31, k=(l>>5)*8+e ; B col=l&31, k=(l>>5)*8+e
//   C/D: col=l&31, row=(r&3)+8*(r>>2)+4*(l>>5)
// Swapped S^T = K*Q^T puts q on lane (col), so P stays lane-local for PV's
// A-operand; per 16-t slot the frag is 4 cvt_pk + 2 permlane32_swap.
// Rowsum via ones-MFMA: its D layout == O's D layout -> epilogue is direct.
// ---------------------------------------------------------------------------
__launch_bounds__(256)
__global__ void mha_attn(const bf16* __restrict__ Qb, const bf16* __restrict__ Kb,
                         const bf16* __restrict__ Vt, float* __restrict__ out) {
    __shared__ __align__(16) bf16 Ks[2][64 * 64];       // 16 KB
    __shared__ __align__(16) bf16 Vs[2][64 * 64];       // 16 KB (d-major V^T)

    const int lane = threadIdx.x & 63;
    const int wave = threadIdx.x >> 6;
    const int l31  = lane & 31;
    const int hi   = lane >> 5;

    const int hh = blockIdx.y;
    const int q0 = blockIdx.x * 128 + wave * 32;

    const bf16* Qh = Qb + (size_t)hh * SEQ * HEAD_DIM;
    const bf16* Kh = Kb + (size_t)hh * SEQ * HEAD_DIM;
    const bf16* Vh = Vt + (size_t)hh * HEAD_DIM * SEQ;

    // staging: 512 chunks of 16B per 64x64 tile; 256 threads stage 2 each.
    // LDS[row][c] <- G[row][c ^ (row&7)]  (source-swizzled, dest linear)
    const int sg0   = wave * 64 + lane;          // 0..255
    const int srow0 = sg0 >> 3;                  // 0..31  (r adds +32, same &7)
    const int sgc   = (sg0 & 7) ^ (srow0 & 7);

    // Q fragments (B-operand of S^T): qf[ks][e] = Q[q0+l31][ks*16 + hi*8 + e]
    bf16x8 qf[4];
#pragma unroll
    for (int ks = 0; ks < 4; ++ks)
        qf[ks] = *(const bf16x8*)(Qh + (size_t)(q0 + l31) * HEAD_DIM + ks * 16 + hi * 8);

    bf16x8 vone;
#pragma unroll
    for (int i = 0; i < 8; ++i) vone[i] = (bf16)1.0f;

    floatx16 o0 = {}, o1 = {}, ol = {};
    const int swz = l31 & 7;

    // prefetch tile 0 into buf 0
#pragma unroll
    for (int r = 0; r < 2; ++r) {
        async16(&Ks[0][(r * 256 + wave * 64) * 8],
                Kh + (size_t)(r * 32 + srow0) * HEAD_DIM + sgc * 8);
        async16(&Vs[0][(r * 256 + wave * 64) * 8],
                Vh + (size_t)(r * 32 + srow0) * SEQ + sgc * 8);
    }
    __syncthreads();

    for (int t0 = 0; t0 < SEQ; t0 += 64) {
        const int cur = (t0 >> 6) & 1, nxt = cur ^ 1;
        if (t0 + 64 < SEQ) {
#pragma unroll
            for (int r = 0; r < 2; ++r) {
                async16(&Ks[nxt][(r * 256 + wave * 64) * 8],
                        Kh + (size_t)(t0 + 64 + r * 32 + srow0) * HEAD_DIM + sgc * 8);
                async16(&Vs[nxt][(r * 256 + wave * 64) * 8],
                        Vh + (size_t)(r * 32 + srow0) * SEQ + t0 + 64 + sgc * 8);
            }
        }

        // K fragments: kf[tt][ks] = K[tt*32+l31][d = ks*16 + hi*8 ..+8]
        bf16x8 kf[2][4];
#pragma unroll
        for (int tt = 0; tt < 2; ++tt)
#pragma unroll
            for (int ks = 0; ks < 4; ++ks)
                kf[tt][ks] = *(const bf16x8*)(&Ks[cur][(tt * 32 + l31) * 64
                                              + (((ks * 2 + hi) ^ swz) * 8)]);

        // S^T tiles: rows t = (r&3)+8*(r>>2)+4*hi (+32*tt), col q = l31
        floatx16 s0 = {}, s1 = {};
#pragma unroll
        for (int ks = 0; ks < 4; ++ks)
            s0 = __builtin_amdgcn_mfma_f32_32x32x16_bf16(kf[0][ks], qf[ks], s0, 0, 0, 0);
#pragma unroll
        for (int ks = 0; ks < 4; ++ks)
            s1 = __builtin_amdgcn_mfma_f32_32x32x16_bf16(kf[1][ks], qf[ks], s1, 0, 0, 0);

        // V fragments: vf[dt][sl] = V[t = sl*16 + hi*8 ..+8][d = dt*32 + l31]
        bf16x8 vf[2][4];
#pragma unroll
        for (int dt = 0; dt < 2; ++dt)
#pragma unroll
            for (int sl = 0; sl < 4; ++sl)
                vf[dt][sl] = *(const bf16x8*)(&Vs[cur][(dt * 32 + l31) * 64
                                              + (((sl * 2 + hi) ^ swz) * 8)]);

        // p = exp2(s); pack PV A-frags in-register.
        // slot sl covers t in [16sl,16sl+16): tile = sl>>1, regs rb..rb+7.
        // lo lane holds t_off={0..3, 8..11}, hi lane t_off={4..7, 12..15}.
        // A-frag needs lane k = 8*hi + e within slot:
        //   u0=pk(p0,p1) u1=pk(p2,p3) u2=pk(p4,p5) u3=pk(p6,p7)
        //   swap(u0,u2): u0.hi <- u2.lo(partner) = t(8,9)   [hi w0 ok]
        //                u2.lo <- u0.hi(partner) = t(4,5)   [lo w2 ok]
        //   swap(u1,u3): u1.hi <- t(10,11), u3.lo <- t(6,7)
        //   frag words = [u0,u1,u2,u3] -> lo: t(0..7), hi: t(8..15)  QED
        bf16x8 pa[4];
#pragma unroll
        for (int sl = 0; sl < 4; ++sl) {
            const floatx16 sv = (sl < 2) ? s0 : s1;
            const int rb = 8 * (sl & 1);
            float p0 = __builtin_amdgcn_exp2f(sv[rb + 0]);
            float p1 = __builtin_amdgcn_exp2f(sv[rb + 1]);
            float p2 = __builtin_amdgcn_exp2f(sv[rb + 2]);
            float p3 = __builtin_amdgcn_exp2f(sv[rb + 3]);
            float p4 = __builtin_amdgcn_exp2f(sv[rb + 4]);
            float p5 = __builtin_amdgcn_exp2f(sv[rb + 5]);
            float p6 = __builtin_amdgcn_exp2f(sv[rb + 6]);
            float p7 = __builtin_amdgcn_exp2f(sv[rb + 7]);
            unsigned u0 = cvtpk_bf16(p0, p1);
            unsigned u1 = cvtpk_bf16(p2, p3);
            unsigned u2 = cvtpk_bf16(p4, p5);
            unsigned u3 = cvtpk_bf16(p6, p7);
            permswap(u0, u2);
            permswap(u1, u3);
            uint32x4 w;
            w[0] = u0; w[1] = u1; w[2] = u2; w[3] = u3;
            pa[sl] = __builtin_bit_cast(bf16x8, w);
        }

        // O += P V ; ol += P 1   (ones-MFMA rowsum lands in O's layout)
#pragma unroll
        for (int sl = 0; sl < 4; ++sl) {
            o0 = __builtin_amdgcn_mfma_f32_32x32x16_bf16(pa[sl], vf[0][sl], o0, 0, 0, 0);
            o1 = __builtin_amdgcn_mfma_f32_32x32x16_bf16(pa[sl], vf[1][sl], o1, 0, 0, 0);
            ol = __builtin_amdgcn_mfma_f32_32x32x16_bf16(pa[sl], vone, ol, 0, 0, 0);
        }
        __syncthreads();   // buffer handoff; drains prefetch issued this iter
    }

    // epilogue: O rows q = q0 + (r&3)+8*(r>>2)+4*hi, cols d = dt*32 + l31
#pragma unroll
    for (int r = 0; r < 16; ++r) {
        const int q = q0 + (r & 3) + 8 * (r >> 2) + 4 * hi;
        const float inv = 1.0f / ol[r];
        out[(size_t)q * (NUM_HEADS * HEAD_DIM) + hh * 64 + l31]      = o0[r] * inv;
        out[(size_t)q * (NUM_HEADS * HEAD_DIM) + hh * 64 + 32 + l31] = o1[r] * inv;
    }
}

extern "C" void kernel_launch(void* const* d_in, const int* in_sizes, int n_in,
                              void* d_out, int out_size, void* d_ws, size_t ws_size,
                              hipStream_t stream) {
    const float* h  = (const float*)d_in[0];
    const float* Wq = (const float*)d_in[1];
    const float* Wk = (const float*)d_in[2];
    const float* Wv = (const float*)d_in[3];
    const float* bq = (const float*)d_in[4];
    const float* bk = (const float*)d_in[5];
    const float* bv = (const float*)d_in[6];
    float* out = (float*)d_out;

    char* ws = (char*)d_ws;
    const size_t MB = 1024 * 1024;
    bf16* hb = (bf16*)(ws);
    bf16* Wt = (bf16*)(ws + 8 * MB);
    bf16* Qb = (bf16*)(ws + 14 * MB);
    bf16* Kb = (bf16*)(ws + 22 * MB);
    bf16* Vt = (bf16*)(ws + 30 * MB);

    mha_conv_h<<<(SEQ * IN_DIM / 4) / 256, 256, 0, stream>>>(h, hb);
    mha_conv_wt<<<dim3(16, 16, 3), 256, 0, stream>>>(Wq, Wk, Wv, Wt);
    mha_qkv_gemm<<<dim3(SEQ / 128, (3 * IN_DIM) / 128), 256, 0, stream>>>(
        hb, Wt, bq, bk, bv, Qb, Kb, Vt);
    mha_attn<<<dim3(SEQ / 128, NUM_HEADS), 256, 0, stream>>>(Qb, Kb, Vt, out);
}

// Round 4
// 206.508 us; speedup vs baseline: 1.0242x; 1.0242x over previous
//
#include <hip/hip_runtime.h>
#include <hip/hip_bf16.h>

#define IN_DIM    1024
#define HEAD_DIM  64
#define NUM_HEADS 16
#define SEQ       4096

// 1/sqrt(64) * log2(e), folded into Q (fp32, pre-bf16-cast). Softmax computed
// with exp2 (v_exp_f32 IS 2^x) -> no per-element ln2 prescale mul in attn.
#define QSCALE 0.18033688011112042f

typedef __bf16 bf16;
typedef __attribute__((ext_vector_type(4))) __bf16 bf16x4;
typedef __attribute__((ext_vector_type(8))) __bf16 bf16x8;
typedef __attribute__((ext_vector_type(4))) float floatx4;
typedef __attribute__((ext_vector_type(16))) float floatx16;
typedef __attribute__((ext_vector_type(4))) unsigned uint32x4;

__device__ __forceinline__ void async16(bf16* lds, const bf16* g) {
    __builtin_amdgcn_global_load_lds(
        (const __attribute__((address_space(1))) unsigned int*)g,
        (__attribute__((address_space(3))) unsigned int*)lds, 16, 0, 0);
}

__device__ __forceinline__ unsigned cvtpk_bf16(float lo, float hi) {
    unsigned r;
    asm("v_cvt_pk_bf16_f32 %0, %1, %2" : "=v"(r) : "v"(lo), "v"(hi));
    return r;
}

// v_permlane32_swap_b32 vdst, vsrc (CDNA4): vdst[32:63] <-> vsrc[0:31]
__device__ __forceinline__ void permswap(unsigned& a, unsigned& b) {
    asm("v_permlane32_swap_b32 %0, %1" : "+v"(a), "+v"(b));
}

// ---------------------------------------------------------------------------
// ws layout: hb @0 (8MB) | Wt @8MB (6MB, n-major) | Qb @14MB | Kb @22MB | Vt @30MB
// ---------------------------------------------------------------------------

__global__ void mha_conv_h(const float* __restrict__ h, bf16* __restrict__ hb) {
    int i = blockIdx.x * blockDim.x + threadIdx.x;
    float4 v = ((const float4*)h)[i];
    bf16x4 r;
    r[0] = (bf16)v.x; r[1] = (bf16)v.y; r[2] = (bf16)v.z; r[3] = (bf16)v.w;
    ((bf16x4*)hb)[i] = r;
}

__global__ void mha_conv_wt(const float* __restrict__ Wq, const float* __restrict__ Wk,
                            const float* __restrict__ Wv, bf16* __restrict__ Wt) {
    __shared__ bf16 tile[64][65];
    const int mat = blockIdx.z;
    const float* W = (mat == 0) ? Wq : (mat == 1) ? Wk : Wv;
    const int k0 = blockIdx.y * 64, n0 = blockIdx.x * 64;
    const int tn = threadIdx.x & 63, tq = threadIdx.x >> 6;
#pragma unroll
    for (int i = 0; i < 16; ++i) {
        int kk = tq + i * 4;
        tile[kk][tn] = (bf16)W[(size_t)(k0 + kk) * 1024 + n0 + tn];
    }
    __syncthreads();
#pragma unroll
    for (int i = 0; i < 16; ++i) {
        int nn = tq + i * 4;
        Wt[((size_t)mat << 20) + (size_t)(n0 + nn) * 1024 + k0 + tn] = tile[tn][nn];
    }
}

// ---------------------------------------------------------------------------
// QKV GEMM, m97-style: 128x128 tile, BK=32, global_load_lds staging,
// XOR-swizzled chunks so frag ds_read_b128 lands 2-way (free).  UNCHANGED.
// ---------------------------------------------------------------------------
__launch_bounds__(256)
__global__ void mha_qkv_gemm(const bf16* __restrict__ hb, const bf16* __restrict__ Wt,
                             const float* __restrict__ bq, const float* __restrict__ bk,
                             const float* __restrict__ bv,
                             bf16* __restrict__ Qb, bf16* __restrict__ Kb,
                             bf16* __restrict__ Vt) {
    __shared__ __align__(16) bf16 As[128 * 32];
    __shared__ __align__(16) bf16 Bs[128 * 32];

    const int lane = threadIdx.x & 63;
    const int wave = threadIdx.x >> 6;
    const int l16  = lane & 15;
    const int quad = lane >> 4;
    const int wm   = wave & 1;
    const int wn   = wave >> 1;

    const int m0  = blockIdx.x * 128;
    const int n0  = blockIdx.y * 128;
    const int mat = n0 >> 10;
    const int nc0 = n0 & 1023;

    const bf16* Wp = Wt + ((size_t)mat << 20);

    floatx4 acc[4][4] = {};
    const int swz = (l16 >> 1) & 3;

    for (int k0 = 0; k0 < IN_DIM; k0 += 32) {
#pragma unroll
        for (int r = 0; r < 2; ++r) {
            int g = wave * 128 + r * 64 + lane;
            int row = g >> 2, c = g & 3;
            int gc = c ^ ((row >> 1) & 3);
            bf16* ldsbase_a = As + (size_t)(wave * 128 + r * 64) * 8;
            bf16* ldsbase_b = Bs + (size_t)(wave * 128 + r * 64) * 8;
            async16(ldsbase_a, hb + (size_t)(m0 + row) * IN_DIM + k0 + gc * 8);
            async16(ldsbase_b, Wp + (size_t)(nc0 + row) * IN_DIM + k0 + gc * 8);
        }
        __syncthreads();

        bf16x8 af[4], bf[4];
#pragma unroll
        for (int mt = 0; mt < 4; ++mt)
            af[mt] = *(const bf16x8*)(As + (size_t)(wm * 64 + mt * 16 + l16) * 32
                                      + ((quad ^ swz) * 8));
#pragma unroll
        for (int nt = 0; nt < 4; ++nt)
            bf[nt] = *(const bf16x8*)(Bs + (size_t)(wn * 64 + nt * 16 + l16) * 32
                                      + ((quad ^ swz) * 8));
#pragma unroll
        for (int mt = 0; mt < 4; ++mt)
#pragma unroll
            for (int nt = 0; nt < 4; ++nt)
                acc[mt][nt] = __builtin_amdgcn_mfma_f32_16x16x32_bf16(af[mt], bf[nt],
                                                                      acc[mt][nt], 0, 0, 0);
        __syncthreads();
    }

    const float* bias = (mat == 0) ? bq : (mat == 1) ? bk : bv;
#pragma unroll
    for (int nt = 0; nt < 4; ++nt) {
        int nc = nc0 + wn * 64 + nt * 16 + l16;
        float bb = bias[nc];
        int head = nc >> 6, d = nc & 63;
#pragma unroll
        for (int mt = 0; mt < 4; ++mt)
#pragma unroll
            for (int r = 0; r < 4; ++r) {
                int srow = m0 + wm * 64 + mt * 16 + quad * 4 + r;
                float v = acc[mt][nt][r] + bb;
                if (mat == 0)
                    Qb[((size_t)head * SEQ + srow) * HEAD_DIM + d] = (bf16)(v * QSCALE);
                else if (mat == 1)
                    Kb[((size_t)head * SEQ + srow) * HEAD_DIM + d] = (bf16)v;
                else
                    Vt[((size_t)head * HEAD_DIM + d) * SEQ + srow] = (bf16)v;
            }
    }
}

// ---------------------------------------------------------------------------
// Attention v3b: 8 waves x 32 q-rows (256 q/block, 1 block/CU), 32x32x16 MFMA,
// in-register P transpose (verified R2).  R3 bug: grid was 16 instead of 256
// blocks (launch-config typo) -- 15/16 of output never written.  Fixed.
//   * counted-vmcnt pipeline (T4): prefetch distance 2, 3-buffer rotation,
//     raw s_barrier, NEVER vmcnt(0) in the main loop.
//   * 256 q-rows per staged tile: halves total staging traffic vs R2.
//   * XCD-head swizzle: each XCD owns 2 heads -> K/V (4MB) L2-resident.
// Wait ladder (2 DMA instrs per tile per wave): prologue vmcnt(0) once;
// steady iter t stages tile t+2 then vmcnt(4) (tiles t+1,t+2 in flight,
// tile t landed); t=62 -> vmcnt(2); t=63 -> vmcnt(0).
// ---------------------------------------------------------------------------
__launch_bounds__(512)
__global__ void mha_attn(const bf16* __restrict__ Qb, const bf16* __restrict__ Kb,
                         const bf16* __restrict__ Vt, float* __restrict__ out) {
    __shared__ __align__(16) bf16 Ks[3][64 * 64];       // 24 KB
    __shared__ __align__(16) bf16 Vs[3][64 * 64];       // 24 KB (d-major V^T)

    const int lane = threadIdx.x & 63;
    const int wave = threadIdx.x >> 6;
    const int l31  = lane & 31;
    const int hi   = lane >> 5;

    // XCD-head swizzle: 256 blocks; XCD k (= bid%8) gets heads {2k, 2k+1}
    // -> per-XCD K/V working set = 4MB = its L2.
    const int bid = blockIdx.x;
    const int hh  = 2 * (bid & 7) + ((bid >> 3) & 1);
    const int qx  = bid >> 4;
    const int q0  = qx * 256 + wave * 32;

    const bf16* Qh = Qb + (size_t)hh * SEQ * HEAD_DIM;
    const bf16* Kh = Kb + (size_t)hh * SEQ * HEAD_DIM;
    const bf16* Vh = Vt + (size_t)hh * HEAD_DIM * SEQ;

    // staging: 512 chunks of 16B per 64x64 tile; 512 threads stage 1 chunk
    // of K + 1 of V.  LDS[row][cc] <- G[row][cc ^ (row&7)] (source-swizzled,
    // dest linear as global_load_lds requires).
    const int sg   = wave * 64 + lane;           // 0..511
    const int srow = sg >> 3;                    // 0..63
    const int sgc  = (sg & 7) ^ (srow & 7);

    // Q fragments (B-operand of S^T): qf[ks][e] = Q[q0+l31][ks*16 + hi*8 + e]
    bf16x8 qf[4];
#pragma unroll
    for (int ks = 0; ks < 4; ++ks)
        qf[ks] = *(const bf16x8*)(Qh + (size_t)(q0 + l31) * HEAD_DIM + ks * 16 + hi * 8);

    bf16x8 vone;
#pragma unroll
    for (int i = 0; i < 8; ++i) vone[i] = (bf16)1.0f;

    floatx16 o0 = {}, o1 = {}, ol = {};
    const int swz = l31 & 7;

    // prologue: stage tiles 0,1; one-time full drain (also drains qf loads so
    // the in-loop counted vmcnt sees ONLY staging DMAs).
    async16(&Ks[0][wave * 512], Kh + (size_t)srow * HEAD_DIM + sgc * 8);
    async16(&Vs[0][wave * 512], Vh + (size_t)srow * SEQ + 0 + sgc * 8);
    async16(&Ks[1][wave * 512], Kh + (size_t)(64 + srow) * HEAD_DIM + sgc * 8);
    async16(&Vs[1][wave * 512], Vh + (size_t)srow * SEQ + 64 + sgc * 8);
    asm volatile("s_waitcnt vmcnt(0)" ::: "memory");
    __builtin_amdgcn_s_barrier();

    int cur = 0;
    for (int t = 0; t < SEQ / 64; ++t) {
        int pre = cur + 2; if (pre >= 3) pre -= 3;
        if (t + 2 < SEQ / 64) {
            const int tg = (t + 2) * 64;
            async16(&Ks[pre][wave * 512], Kh + (size_t)(tg + srow) * HEAD_DIM + sgc * 8);
            async16(&Vs[pre][wave * 512], Vh + (size_t)srow * SEQ + tg + sgc * 8);
        }
        if (t < SEQ / 64 - 2)      asm volatile("s_waitcnt vmcnt(4)" ::: "memory");
        else if (t == SEQ / 64 - 2) asm volatile("s_waitcnt vmcnt(2)" ::: "memory");
        else                        asm volatile("s_waitcnt vmcnt(0)" ::: "memory");
        __builtin_amdgcn_s_barrier();
        asm volatile("" ::: "memory");

        // ---- compute on buf[cur] (byte-identical to verified R2 body) ----
        // K fragments: kf[tt][ks] = K[tt*32+l31][d = ks*16 + hi*8 ..+8]
        bf16x8 kf[2][4];
#pragma unroll
        for (int tt = 0; tt < 2; ++tt)
#pragma unroll
            for (int ks = 0; ks < 4; ++ks)
                kf[tt][ks] = *(const bf16x8*)(&Ks[cur][(tt * 32 + l31) * 64
                                              + (((ks * 2 + hi) ^ swz) * 8)]);

        // S^T tiles: rows t = (r&3)+8*(r>>2)+4*hi (+32*tt), col q = l31
        floatx16 s0 = {}, s1 = {};
#pragma unroll
        for (int ks = 0; ks < 4; ++ks)
            s0 = __builtin_amdgcn_mfma_f32_32x32x16_bf16(kf[0][ks], qf[ks], s0, 0, 0, 0);
#pragma unroll
        for (int ks = 0; ks < 4; ++ks)
            s1 = __builtin_amdgcn_mfma_f32_32x32x16_bf16(kf[1][ks], qf[ks], s1, 0, 0, 0);

        // V fragments: vf[dt][sl] = V[t = sl*16 + hi*8 ..+8][d = dt*32 + l31]
        bf16x8 vf[2][4];
#pragma unroll
        for (int dt = 0; dt < 2; ++dt)
#pragma unroll
            for (int sl = 0; sl < 4; ++sl)
                vf[dt][sl] = *(const bf16x8*)(&Vs[cur][(dt * 32 + l31) * 64
                                              + (((sl * 2 + hi) ^ swz) * 8)]);

        // p = exp2(s); pack PV A-frags in-register (cvt_pk + permlane32_swap;
        // swap is vdst.hi <-> vsrc.lo, arg order verified in R2).
        bf16x8 pa[4];
#pragma unroll
        for (int sl = 0; sl < 4; ++sl) {
            const floatx16 sv = (sl < 2) ? s0 : s1;
            const int rb = 8 * (sl & 1);
            float p0 = __builtin_amdgcn_exp2f(sv[rb + 0]);
            float p1 = __builtin_amdgcn_exp2f(sv[rb + 1]);
            float p2 = __builtin_amdgcn_exp2f(sv[rb + 2]);
            float p3 = __builtin_amdgcn_exp2f(sv[rb + 3]);
            float p4 = __builtin_amdgcn_exp2f(sv[rb + 4]);
            float p5 = __builtin_amdgcn_exp2f(sv[rb + 5]);
            float p6 = __builtin_amdgcn_exp2f(sv[rb + 6]);
            float p7 = __builtin_amdgcn_exp2f(sv[rb + 7]);
            unsigned u0 = cvtpk_bf16(p0, p1);
            unsigned u1 = cvtpk_bf16(p2, p3);
            unsigned u2 = cvtpk_bf16(p4, p5);
            unsigned u3 = cvtpk_bf16(p6, p7);
            permswap(u0, u2);
            permswap(u1, u3);
            uint32x4 w;
            w[0] = u0; w[1] = u1; w[2] = u2; w[3] = u3;
            pa[sl] = __builtin_bit_cast(bf16x8, w);
        }

        // O += P V ; ol += P 1   (ones-MFMA rowsum lands in O's layout)
#pragma unroll
        for (int sl = 0; sl < 4; ++sl) {
            o0 = __builtin_amdgcn_mfma_f32_32x32x16_bf16(pa[sl], vf[0][sl], o0, 0, 0, 0);
            o1 = __builtin_amdgcn_mfma_f32_32x32x16_bf16(pa[sl], vf[1][sl], o1, 0, 0, 0);
            ol = __builtin_amdgcn_mfma_f32_32x32x16_bf16(pa[sl], vone, ol, 0, 0, 0);
        }
        // ---- end compute ----

        asm volatile("" ::: "memory");
        __builtin_amdgcn_s_barrier();      // reads of buf[cur] done before restage
        cur = cur + 1; if (cur == 3) cur = 0;
    }

    // epilogue: O rows q = q0 + (r&3)+8*(r>>2)+4*hi, cols d = dt*32 + l31
#pragma unroll
    for (int r = 0; r < 16; ++r) {
        const int q = q0 + (r & 3) + 8 * (r >> 2) + 4 * hi;
        const float inv = 1.0f / ol[r];
        out[(size_t)q * (NUM_HEADS * HEAD_DIM) + hh * 64 + l31]      = o0[r] * inv;
        out[(size_t)q * (NUM_HEADS * HEAD_DIM) + hh * 64 + 32 + l31] = o1[r] * inv;
    }
}

extern "C" void kernel_launch(void* const* d_in, const int* in_sizes, int n_in,
                              void* d_out, int out_size, void* d_ws, size_t ws_size,
                              hipStream_t stream) {
    const float* h  = (const float*)d_in[0];
    const float* Wq = (const float*)d_in[1];
    const float* Wk = (const float*)d_in[2];
    const float* Wv = (const float*)d_in[3];
    const float* bq = (const float*)d_in[4];
    const float* bk = (const float*)d_in[5];
    const float* bv = (const float*)d_in[6];
    float* out = (float*)d_out;

    char* ws = (char*)d_ws;
    const size_t MB = 1024 * 1024;
    bf16* hb = (bf16*)(ws);
    bf16* Wt = (bf16*)(ws + 8 * MB);
    bf16* Qb = (bf16*)(ws + 14 * MB);
    bf16* Kb = (bf16*)(ws + 22 * MB);
    bf16* Vt = (bf16*)(ws + 30 * MB);

    mha_conv_h<<<(SEQ * IN_DIM / 4) / 256, 256, 0, stream>>>(h, hb);
    mha_conv_wt<<<dim3(16, 16, 3), 256, 0, stream>>>(Wq, Wk, Wv, Wt);
    mha_qkv_gemm<<<dim3(SEQ / 128, (3 * IN_DIM) / 128), 256, 0, stream>>>(
        hb, Wt, bq, bk, bv, Qb, Kb, Vt);
    // 256 q-rows per block x 16 heads: (SEQ/256) * NUM_HEADS = 256 blocks.
    mha_attn<<<dim3((SEQ / 256) * NUM_HEADS), 512, 0, stream>>>(Qb, Kb, Vt, out);
}